// Round 7
// baseline (1899.307 us; speedup 1.0000x reference)
//
#include <hip/hip_runtime.h>
#include <cstdint>

// LCA model constants
#define T_STEPS 3000
#define S_SIMS  1000
#define D_DIM   16
#define NJ      (S_SIMS * D_DIM)          // 16000 flat (s,d) rows
#define ROW     (T_STEPS + 1)             // 3001 outputs per row
#define HALF_OUT ((long long)NJ * ROW)

#define NSIMB  250                        // sim blocks (4 sims each)
#define GRID   256                        // total blocks (6 pure fillers)
#define NPROD  15                         // producer waves per sim block
#define DEPTH  128                        // LDS noise ring (steps), pow2
#define BATCH  8                          // consumer speculation batch
#define DCAP   128                        // deferred-row list capacity
#define SQSTEP 0.03162277660168379f       // sqrt(0.001)

__device__ uint2    g_keys[T_STEPS];
__device__ int      g_tf_pub[S_SIMS];               // -1 until published
__device__ unsigned g_c1;                           // fill work cursor
__device__ float    g_ws_pre[(size_t)T_STEPS * NJ]; // [t][j] prefix only

// ---------------------------------------------------------------------------
// Threefry-2x32 (20 rounds), bit-exact vs jax._src.prng (partitionable mode)
// ---------------------------------------------------------------------------
__device__ __forceinline__ uint32_t rotl32(uint32_t v, uint32_t d) {
  return (v << d) | (v >> (32u - d));
}
__device__ __forceinline__ void threefry2x32(uint32_t k0, uint32_t k1,
                                             uint32_t& x0, uint32_t& x1) {
  uint32_t k2 = k0 ^ k1 ^ 0x1BD11BDAu;
  x0 += k0; x1 += k1;
#define TFR(r) { x0 += x1; x1 = rotl32(x1, r); x1 ^= x0; }
  TFR(13u) TFR(15u) TFR(26u) TFR(6u)
  x0 += k1; x1 += k2 + 1u;
  TFR(17u) TFR(29u) TFR(16u) TFR(24u)
  x0 += k2; x1 += k0 + 2u;
  TFR(13u) TFR(15u) TFR(26u) TFR(6u)
  x0 += k0; x1 += k1 + 3u;
  TFR(17u) TFR(29u) TFR(16u) TFR(24u)
  x0 += k1; x1 += k2 + 4u;
  TFR(13u) TFR(15u) TFR(26u) TFR(6u)
  x0 += k2; x1 += k0 + 5u;
#undef TFR
}

// bits -> N(0,1): jax.random.normal f32 path (XLA ErfInv32 / Giles), with
// log1p(-u*u) = ln2*log2((1-u)(1+u)) via HW log (validated r6: absmax 0.002).
__device__ __forceinline__ float bits_to_normal(uint32_t bits) {
  uint32_t fb = (bits >> 9) | 0x3f800000u;
  float f = __uint_as_float(fb) - 1.0f;
  const float lo = -0.99999994f;
  float u = f * 2.0f + lo;
  u = fmaxf(lo, u);
  float w = -0.6931471805599453f * __log2f((1.0f - u) * (1.0f + u));
  float p;
  if (w < 5.0f) {
    w = w - 2.5f;
    p = 2.81022636e-08f;
    p = fmaf(p, w, 3.43273939e-07f);
    p = fmaf(p, w, -3.5233877e-06f);
    p = fmaf(p, w, -4.39150654e-06f);
    p = fmaf(p, w, 0.00021858087f);
    p = fmaf(p, w, -0.00125372503f);
    p = fmaf(p, w, -0.00417768164f);
    p = fmaf(p, w, 0.246640727f);
    p = fmaf(p, w, 1.50140941f);
  } else {
    w = sqrtf(w) - 3.0f;
    p = -0.000200214257f;
    p = fmaf(p, w, 0.000100950558f);
    p = fmaf(p, w, 0.00134934322f);
    p = fmaf(p, w, -0.00367342844f);
    p = fmaf(p, w, 0.00573950773f);
    p = fmaf(p, w, -0.0076224613f);
    p = fmaf(p, w, 0.00943887047f);
    p = fmaf(p, w, 1.00167406f);
    p = fmaf(p, w, 2.83297682f);
  }
  return 1.41421356237f * (p * u);
}

__device__ __forceinline__ float noise_at(int t, int j) {
  uint2 k = g_keys[t];
  uint32_t x0 = 0u, x1 = (uint32_t)j;
  threefry2x32(k.x, k.y, x0, x1);
  return bits_to_normal(x0 ^ x1);
}

// ---------------------------------------------------------------------------
// init: per-step keys (partitionable fold of split(key(42),T)) + queue state
// ---------------------------------------------------------------------------
__global__ void init_kernel() {
  int i = blockIdx.x * blockDim.x + threadIdx.x;
  if (i < T_STEPS) {
    uint32_t x0 = 0u, x1 = (uint32_t)i;
    threefry2x32(0u, 42u, x0, x1);
    g_keys[i] = make_uint2(x0, x1);
  }
  if (i < S_SIMS) g_tf_pub[i] = -1;
  if (i == 0) g_c1 = 0u;
}

// ---------------------------------------------------------------------------
// DPP reductions within each 16-lane row (one sim).
// ---------------------------------------------------------------------------
template <int CTRL>
__device__ __forceinline__ float dpp_movf(float v) {
  return __int_as_float(
      __builtin_amdgcn_update_dpp(0, __float_as_int(v), CTRL, 0xF, 0xF, true));
}
__device__ __forceinline__ float row16_sum(float a) {
  float s = a;
  s += dpp_movf<0xB1>(s);
  s += dpp_movf<0x4E>(s);
  s += dpp_movf<0x124>(s);
  s += dpp_movf<0x128>(s);
  return s;
}
__device__ __forceinline__ float row16_max(float a) {  // a >= 0
  float m = a;
  m = fmaxf(m, dpp_movf<0xB1>(m));
  m = fmaxf(m, dpp_movf<0x4E>(m));
  m = fmaxf(m, dpp_movf<0x124>(m));
  m = fmaxf(m, dpp_movf<0x128>(m));
  return m;
}

// ---------------------------------------------------------------------------
// Row fill: out[pre|act][j][0..3000]; prefix from ws, frozen tail = ws[tf-1].
// ---------------------------------------------------------------------------
__device__ __forceinline__ void fill_row(float* __restrict__ out, int j, int tf) {
  float* __restrict__ pre_out = out + (size_t)j * ROW;
  float* __restrict__ act_out = pre_out + HALF_OUT;
  const float vlast = g_ws_pre[(size_t)(tf - 1) * NJ + j];
  for (int idx = threadIdx.x; idx < ROW; idx += 1024) {
    float v;
    if (idx == 0) v = 0.0f;
    else {
      int te = idx - 1;
      v = (te < tf) ? g_ws_pre[(size_t)te * NJ + j] : vlast;
    }
    pre_out[idx] = v;
    act_out[idx] = fmaxf(v, 0.0f);
  }
}

// ---------------------------------------------------------------------------
// Fused persistent kernel: 250 sim blocks (1 consumer + 15 producer waves)
// that convert into output fillers when their sims die; 6 pure filler blocks.
// Cross-block: tf published with agent release; fillers acquire before ws.
// ---------------------------------------------------------------------------
__global__ __launch_bounds__(1024, 4) void fused_kernel(const float* __restrict__ ff,
                                                        float* __restrict__ out) {
  __shared__ float sh_nbuf[DEPTH][64];
  __shared__ volatile unsigned char sh_rdy[DEPTH];
  __shared__ volatile unsigned sh_cons;   // consumer watermark
  __shared__ volatile unsigned sh_done;
  __shared__ int sh_d[DCAP];              // deferred rows (thread0-owned)
  __shared__ int sh_dn;
  __shared__ int sh_pick;
  __shared__ int sh_claim;
  __shared__ int sh_c4[4];

  const int tid  = threadIdx.x;
  const int lane = tid & 63;
  const int wid  = tid >> 6;

  for (int q = tid; q < DEPTH; q += 1024) sh_rdy[q] = 0;
  if (tid == 0) { sh_cons = 0u; sh_done = 0u; sh_dn = 0; }
  __syncthreads();

  if (blockIdx.x < NSIMB) {
    const int j = blockIdx.x * 64 + lane;   // s = j>>4, d = j&15

    if (wid == 0) {
      // ================= consumer: LCA dynamics, batch-8 speculative ========
      __builtin_amdgcn_s_setprio(1);
      const float ffv = ff[j];
      float pre = 0.0f, act = 0.0f;
      bool dead = false;
      float n[BATCH], a[BATCH];
      volatile unsigned* rdy32 = (volatile unsigned*)sh_rdy;

#define WAITLOAD(T0)                                                          \
      {                                                                       \
        unsigned u_ = (((unsigned)(T0)) & (DEPTH - 1)) >> 2;                  \
        while (rdy32[u_] != 0x01010101u || rdy32[u_ + 1] != 0x01010101u)      \
          __builtin_amdgcn_s_sleep(1);                                        \
        _Pragma("unroll")                                                     \
        for (int k_ = 0; k_ < BATCH; ++k_)                                    \
          n[k_] = sh_nbuf[(((T0) & (DEPTH - 1)) + k_)][lane];                 \
        asm volatile("s_waitcnt lgkmcnt(0)" ::: "memory");                    \
        if (lane == 0) { rdy32[u_] = 0u; rdy32[u_ + 1] = 0u; }                \
        asm volatile("s_waitcnt lgkmcnt(0)" ::: "memory");                    \
        if (lane == 0) sh_cons = (unsigned)((T0) + BATCH);                    \
      }

      WAITLOAD(0);
      int t0 = 0;
      while (true) {
        float bmax = 0.0f;
        float* __restrict__ wsp = g_ws_pre + (size_t)t0 * NJ + j;
#pragma unroll
        for (int k = 0; k < BATCH; ++k) {
          float s  = row16_sum(act);
          float e1 = fmaf(-0.1f, pre, ffv);          // ff - leak*pre
          float e2 = fmaf(-0.1f, s - act, e1);       // - competition*(sum-others)
          pre = fmaf(e2, 0.01f, pre);                // + expr*dt
          pre = fmaf(n[k], SQSTEP, pre);             // + dw*sqrt(0.001)
          act = fmaxf(pre, 0.0f);
          a[k] = act;
          bmax = fmaxf(bmax, act);
          if (!dead) wsp[(size_t)k * NJ] = pre;
        }

        if (__any(bmax >= 1.0f)) {                   // rare: <=4x per wave
          bool found = dead;
          int ctf = 0;
#pragma unroll
          for (int k = 0; k < BATCH; ++k) {
            float m = row16_max(a[k]);               // row-uniform
            if (!found && m >= 1.0f) { found = true; ctf = t0 + k + 1; }
          }
          if (found && !dead) {                      // this row just crossed
            dead = true;
            pre = -1e30f;                            // relu pins act=0 forever
            act = 0.0f;
            if ((lane & 15) == 0)
              __hip_atomic_store(&g_tf_pub[j >> 4], ctf,
                                 __ATOMIC_RELEASE, __HIP_MEMORY_SCOPE_AGENT);
          }
          if (__all(dead)) break;
        }

        t0 += BATCH;
        if (t0 >= T_STEPS) break;
        WAITLOAD(t0);
      }
#undef WAITLOAD
      if (!dead && (lane & 15) == 0)                 // horizon survivors
        __hip_atomic_store(&g_tf_pub[j >> 4], T_STEPS,
                           __ATOMIC_RELEASE, __HIP_MEMORY_SCOPE_AGENT);
      if (lane == 0) sh_done = 1u;
      __builtin_amdgcn_s_setprio(0);
    } else {
      // ================= producers: noise for t ≡ p (mod NPROD) =============
      const int p = wid - 1;
      bool quit = false;
      for (int t = p; t < T_STEPS; t += NPROD) {
        if (sh_done) break;
        float nv = noise_at(t, j);
        if (t >= DEPTH) {
          while ((unsigned)t >= sh_cons + DEPTH) {
            if (sh_done) { quit = true; break; }
            __builtin_amdgcn_s_sleep(4);
          }
          if (quit) break;
        }
        sh_nbuf[t & (DEPTH - 1)][lane] = nv;
        asm volatile("s_waitcnt lgkmcnt(0)" ::: "memory");
        if (lane == 0) sh_rdy[t & (DEPTH - 1)] = 1;
      }
    }
    __syncthreads();   // whole block re-converges, then becomes a filler
  }

  // ======================= filler phase (all blocks) ========================
  bool cursor_open = true;
  while (true) {
    // ---- A: probe deferred rows in parallel, fill one if ready ----
    if (tid == 0) sh_pick = -1;
    __syncthreads();
    int dn = sh_dn;
    if (tid < dn) {
      int jj = sh_d[tid];
      if (__hip_atomic_load(&g_tf_pub[jj >> 4], __ATOMIC_RELAXED,
                            __HIP_MEMORY_SCOPE_AGENT) >= 0)
        sh_pick = tid;                               // benign race, any wins
    }
    __syncthreads();
    int pick = sh_pick;
    if (pick >= 0) {
      int j = sh_d[pick];
      if (tid == 0) { sh_d[pick] = sh_d[dn - 1]; sh_dn = dn - 1; }
      int tf = __hip_atomic_load(&g_tf_pub[j >> 4], __ATOMIC_ACQUIRE,
                                 __HIP_MEMORY_SCOPE_AGENT);
      __syncthreads();
      fill_row(out, j, tf);
      continue;
    }
    // ---- B: claim 4 new rows from the global cursor ----
    if (cursor_open && dn <= DCAP - 4) {
      if (tid == 0) sh_claim = (int)atomicAdd(&g_c1, 4u);
      __syncthreads();
      int base = sh_claim;
      if (base >= NJ) {
        cursor_open = false;
        if (dn == 0) break;
        continue;
      }
      if (tid < 4) {
        int i = base + tid;
        int enc = -1;
        if (i < NJ) {
          int jj = (int)(((long long)i * 997) % NJ);  // scatter sims across claims
          int rdy = __hip_atomic_load(&g_tf_pub[jj >> 4], __ATOMIC_RELAXED,
                                      __HIP_MEMORY_SCOPE_AGENT) >= 0;
          enc = rdy ? jj : (-2 - jj);
        }
        sh_c4[tid] = enc;
      }
      __syncthreads();
      if (tid == 0) {
        int d2 = sh_dn;
        for (int q = 0; q < 4; ++q) {
          int c = sh_c4[q];
          if (c <= -2) sh_d[d2++] = -2 - c;
        }
        sh_dn = d2;
      }
      __syncthreads();
      for (int q = 0; q < 4; ++q) {
        int c = sh_c4[q];
        if (c >= 0) {
          int tf = __hip_atomic_load(&g_tf_pub[c >> 4], __ATOMIC_ACQUIRE,
                                     __HIP_MEMORY_SCOPE_AGENT);
          fill_row(out, c, tf);
        }
      }
      continue;
    }
    if (!cursor_open && dn == 0) break;
    __builtin_amdgcn_s_sleep(32);
    __syncthreads();
  }
}

// ---------------------------------------------------------------------------
extern "C" void kernel_launch(void* const* d_in, const int* in_sizes, int n_in,
                              void* d_out, int out_size, void* d_ws, size_t ws_size,
                              hipStream_t stream) {
  const float* ff = (const float*)d_in[0];
  float* out = (float*)d_out;

  init_kernel<<<dim3(16), dim3(256), 0, stream>>>();
  fused_kernel<<<dim3(GRID), dim3(1024), 0, stream>>>(ff, out);
}

// Round 8
// 286.947 us; speedup vs baseline: 6.6190x; 6.6190x over previous
//
#include <hip/hip_runtime.h>
#include <cstdint>

// LCA model constants
#define T_STEPS 3000
#define S_SIMS  1000
#define D_DIM   16
#define NJ      (S_SIMS * D_DIM)          // 16000 flat (s,d) rows
#define ROW     (T_STEPS + 1)             // 3001 outputs per row
#define HALF_OUT ((long long)NJ * ROW)

#define NSIMB  250                        // sim blocks (4 sims each, 64 lanes)
#define GRID   384                        // total blocks; 250.. are pure fillers
#define NPROD  7                          // producer waves per sim block (r6-proven)
#define DEPTH  32                         // LDS noise ring slots, pow2 (r6-proven)
#define BATCH  8                          // consumer speculation batch (r6-proven)
#define SQSTEP 0.03162277660168379f       // sqrt(0.001)

__device__ uint2    g_keys[T_STEPS];
__device__ int      g_tf_pub[S_SIMS];               // -1 until published
__device__ unsigned g_c1;                           // fill work cursor
__device__ float    g_ws_pre[(size_t)T_STEPS * NJ]; // [t][j] prefix only

// ---------------------------------------------------------------------------
// Threefry-2x32 (20 rounds), bit-exact vs jax._src.prng (partitionable mode)
// ---------------------------------------------------------------------------
__device__ __forceinline__ uint32_t rotl32(uint32_t v, uint32_t d) {
  return (v << d) | (v >> (32u - d));
}
__device__ __forceinline__ void threefry2x32(uint32_t k0, uint32_t k1,
                                             uint32_t& x0, uint32_t& x1) {
  uint32_t k2 = k0 ^ k1 ^ 0x1BD11BDAu;
  x0 += k0; x1 += k1;
#define TFR(r) { x0 += x1; x1 = rotl32(x1, r); x1 ^= x0; }
  TFR(13u) TFR(15u) TFR(26u) TFR(6u)
  x0 += k1; x1 += k2 + 1u;
  TFR(17u) TFR(29u) TFR(16u) TFR(24u)
  x0 += k2; x1 += k0 + 2u;
  TFR(13u) TFR(15u) TFR(26u) TFR(6u)
  x0 += k0; x1 += k1 + 3u;
  TFR(17u) TFR(29u) TFR(16u) TFR(24u)
  x0 += k1; x1 += k2 + 4u;
  TFR(13u) TFR(15u) TFR(26u) TFR(6u)
  x0 += k2; x1 += k0 + 5u;
#undef TFR
}

// bits -> N(0,1): jax.random.normal f32 path (XLA ErfInv32 / Giles), with
// log1p(-u*u) = ln2*log2((1-u)(1+u)) via HW log (validated r6: absmax 0.002).
__device__ __forceinline__ float bits_to_normal(uint32_t bits) {
  uint32_t fb = (bits >> 9) | 0x3f800000u;
  float f = __uint_as_float(fb) - 1.0f;
  const float lo = -0.99999994f;
  float u = f * 2.0f + lo;
  u = fmaxf(lo, u);
  float w = -0.6931471805599453f * __log2f((1.0f - u) * (1.0f + u));
  float p;
  if (w < 5.0f) {
    w = w - 2.5f;
    p = 2.81022636e-08f;
    p = fmaf(p, w, 3.43273939e-07f);
    p = fmaf(p, w, -3.5233877e-06f);
    p = fmaf(p, w, -4.39150654e-06f);
    p = fmaf(p, w, 0.00021858087f);
    p = fmaf(p, w, -0.00125372503f);
    p = fmaf(p, w, -0.00417768164f);
    p = fmaf(p, w, 0.246640727f);
    p = fmaf(p, w, 1.50140941f);
  } else {
    w = sqrtf(w) - 3.0f;
    p = -0.000200214257f;
    p = fmaf(p, w, 0.000100950558f);
    p = fmaf(p, w, 0.00134934322f);
    p = fmaf(p, w, -0.00367342844f);
    p = fmaf(p, w, 0.00573950773f);
    p = fmaf(p, w, -0.0076224613f);
    p = fmaf(p, w, 0.00943887047f);
    p = fmaf(p, w, 1.00167406f);
    p = fmaf(p, w, 2.83297682f);
  }
  return 1.41421356237f * (p * u);
}

__device__ __forceinline__ float noise_at(int t, int j) {
  uint2 k = g_keys[t];
  uint32_t x0 = 0u, x1 = (uint32_t)j;
  threefry2x32(k.x, k.y, x0, x1);
  return bits_to_normal(x0 ^ x1);
}

// ---------------------------------------------------------------------------
// init: per-step keys (partitionable fold of split(key(42),T)) + queue state
// ---------------------------------------------------------------------------
__global__ void init_kernel() {
  int i = blockIdx.x * blockDim.x + threadIdx.x;
  if (i < T_STEPS) {
    uint32_t x0 = 0u, x1 = (uint32_t)i;
    threefry2x32(0u, 42u, x0, x1);
    g_keys[i] = make_uint2(x0, x1);
  }
  if (i < S_SIMS) g_tf_pub[i] = -1;
  if (i == 0) g_c1 = 0u;
}

// ---------------------------------------------------------------------------
// DPP reductions within each 16-lane row (one sim).
// ---------------------------------------------------------------------------
template <int CTRL>
__device__ __forceinline__ float dpp_movf(float v) {
  return __int_as_float(
      __builtin_amdgcn_update_dpp(0, __float_as_int(v), CTRL, 0xF, 0xF, true));
}
__device__ __forceinline__ float row16_sum(float a) {
  float s = a;
  s += dpp_movf<0xB1>(s);
  s += dpp_movf<0x4E>(s);
  s += dpp_movf<0x124>(s);
  s += dpp_movf<0x128>(s);
  return s;
}
__device__ __forceinline__ float row16_max(float a) {  // a >= 0
  float m = a;
  m = fmaxf(m, dpp_movf<0xB1>(m));
  m = fmaxf(m, dpp_movf<0x4E>(m));
  m = fmaxf(m, dpp_movf<0x124>(m));
  m = fmaxf(m, dpp_movf<0x128>(m));
  return m;
}

// ---------------------------------------------------------------------------
// Fused kernel: blocks [0,250) = r6-style sim (1 consumer + 7 producer waves,
// 512 threads); all waves fall through to a per-wave output-fill loop.
// tf published per-sim with agent release; fillers acquire before ws reads
// (protocol validated in r7 under harness replays).
// ---------------------------------------------------------------------------
__global__ __launch_bounds__(512) void fused_kernel(const float* __restrict__ ff,
                                                    float* __restrict__ out) {
  __shared__ float sh_nbuf[DEPTH][64];
  __shared__ volatile unsigned sh_prodc[NPROD];  // per-producer completed count
  __shared__ volatile unsigned sh_cons;          // consumer watermark
  __shared__ volatile unsigned sh_done;

  const int tid  = threadIdx.x;
  const int lane = tid & 63;
  const int wid  = tid >> 6;

  if (blockIdx.x < NSIMB) {
    if (tid < NPROD) sh_prodc[tid] = 0u;
    if (tid == 0) { sh_cons = 0u; sh_done = 0u; }
    __syncthreads();
    const int j = blockIdx.x * 64 + lane;        // s = j>>4, d = j&15

    if (wid == 0) {
      // ============ consumer: LCA dynamics, batch-8 speculative (r6) ========
      __builtin_amdgcn_s_setprio(1);
      const float ffv = ff[j];
      float pre = 0.0f, act = 0.0f;
      bool dead = false;
      unsigned Rc = 0;   // steps < Rc are known produced

#define ENSURE(x)                                                     \
      while (Rc <= (unsigned)(x)) {                                   \
        unsigned mn = 0xffffffffu;                                    \
        for (int p_ = 0; p_ < NPROD; ++p_) {                          \
          unsigned lim = (unsigned)p_ + (unsigned)NPROD * sh_prodc[p_]; \
          if (lim < mn) mn = lim;                                     \
        }                                                             \
        Rc = mn;                                                      \
        if (Rc <= (unsigned)(x)) __builtin_amdgcn_s_sleep(2);         \
      }

      float n[BATCH], nn[BATCH], a[BATCH];
      ENSURE(BATCH - 1);
#pragma unroll
      for (int k = 0; k < BATCH; ++k) n[k] = sh_nbuf[k][lane];

      int t0 = 0;
      while (true) {
        if (lane == 0) sh_cons = (unsigned)(t0 + BATCH);
        const bool more = (t0 + BATCH < T_STEPS);
        if (more) {
          ENSURE(t0 + 2 * BATCH - 1);
#pragma unroll
          for (int k = 0; k < BATCH; ++k)
            nn[k] = sh_nbuf[(t0 + BATCH + k) & (DEPTH - 1)][lane];
        }

        float bmax = 0.0f;
        float* __restrict__ wsp = g_ws_pre + (size_t)t0 * NJ + j;
#pragma unroll
        for (int k = 0; k < BATCH; ++k) {
          float s  = row16_sum(act);
          float e1 = fmaf(-0.1f, pre, ffv);          // ff - leak*pre
          float e2 = fmaf(-0.1f, s - act, e1);       // - competition*(sum-self)
          pre = fmaf(e2, 0.01f, pre);                // + expr*dt
          pre = fmaf(n[k], SQSTEP, pre);             // + dw*sqrt(0.001)
          act = fmaxf(pre, 0.0f);
          a[k] = act;
          bmax = fmaxf(bmax, act);
          if (!dead) wsp[(size_t)k * NJ] = pre;
        }

        if (__any(bmax >= 1.0f)) {                   // rare
          bool found = dead;
          int ctf = 0;
#pragma unroll
          for (int k = 0; k < BATCH; ++k) {
            float m = row16_max(a[k]);               // row-uniform
            if (!found && m >= 1.0f) { found = true; ctf = t0 + k + 1; }
          }
          if (found && !dead) {                      // this row just crossed
            dead = true;
            pre = -1e30f;                            // relu pins act=0 forever
            act = 0.0f;
            if ((lane & 15) == 0)
              __hip_atomic_store(&g_tf_pub[j >> 4], ctf,
                                 __ATOMIC_RELEASE, __HIP_MEMORY_SCOPE_AGENT);
          }
          if (__all(dead)) break;
        }

        if (!more) break;
#pragma unroll
        for (int k = 0; k < BATCH; ++k) n[k] = nn[k];
        t0 += BATCH;
      }
#undef ENSURE
      if (!dead && (lane & 15) == 0)                 // horizon survivors
        __hip_atomic_store(&g_tf_pub[j >> 4], T_STEPS,
                           __ATOMIC_RELEASE, __HIP_MEMORY_SCOPE_AGENT);
      if (lane == 0) sh_done = 1u;
      __builtin_amdgcn_s_setprio(0);
    } else {
      // ============ producers: noise for t ≡ p (mod NPROD) (r6) =============
      const int p = wid - 1;
      unsigned count = 0;
      bool quit = false;
      for (int t = p; t < T_STEPS; t += NPROD) {
        if (sh_done) break;
        float nv = noise_at(t, j);
        if (t >= DEPTH) {
          while (true) {
            if (sh_done) { quit = true; break; }
            unsigned pc = sh_cons;
            if ((unsigned)t <= pc + (DEPTH - 1)) break;
            __builtin_amdgcn_s_sleep(4);
          }
          if (quit) break;
        }
        sh_nbuf[t & (DEPTH - 1)][lane] = nv;
        asm volatile("s_waitcnt lgkmcnt(0)" ::: "memory");
        ++count;
        if (lane == 0) sh_prodc[p] = count;
      }
    }
    // fall through to fill phase, per wave (no block re-convergence needed)
  }

  // ================= fill phase: per-wave row claiming ======================
  while (true) {
    unsigned i = 0;
    if (lane == 0) i = atomicAdd(&g_c1, 1u);
    i = (unsigned)__shfl((int)i, 0);
    if (i >= NJ) break;
    const int j = (int)((i * 997u) % (unsigned)NJ);  // scatter: bijective
    const int s = j >> 4;

    int tf = __hip_atomic_load(&g_tf_pub[s], __ATOMIC_RELAXED,
                               __HIP_MEMORY_SCOPE_AGENT);
    while (tf < 0) {                                 // park until sim publishes
      __builtin_amdgcn_s_sleep(8);
      tf = __hip_atomic_load(&g_tf_pub[s], __ATOMIC_RELAXED,
                             __HIP_MEMORY_SCOPE_AGENT);
    }
    (void)__hip_atomic_load(&g_tf_pub[s], __ATOMIC_ACQUIRE,
                            __HIP_MEMORY_SCOPE_AGENT);  // order ws reads

    float* __restrict__ pre_out = out + (size_t)j * ROW;
    float* __restrict__ act_out = pre_out + HALF_OUT;
    const float vlast = g_ws_pre[(size_t)(tf - 1) * NJ + j];
    for (int idx = lane; idx < ROW; idx += 64) {
      float v = 0.0f;
      if (idx > 0) {
        int te = idx - 1;
        v = vlast;
        if (te < tf) v = g_ws_pre[(size_t)te * NJ + j];
      }
      pre_out[idx] = v;
      act_out[idx] = fmaxf(v, 0.0f);
    }
  }
}

// ---------------------------------------------------------------------------
extern "C" void kernel_launch(void* const* d_in, const int* in_sizes, int n_in,
                              void* d_out, int out_size, void* d_ws, size_t ws_size,
                              hipStream_t stream) {
  const float* ff = (const float*)d_in[0];
  float* out = (float*)d_out;

  init_kernel<<<dim3(16), dim3(256), 0, stream>>>();
  fused_kernel<<<dim3(GRID), dim3(512), 0, stream>>>(ff, out);
}

// Round 9
// 180.802 us; speedup vs baseline: 10.5049x; 1.5871x over previous
//
#include <hip/hip_runtime.h>
#include <cstdint>

// LCA model constants
#define T_STEPS 3000
#define S_SIMS  1000
#define D_DIM   16
#define NJ      (S_SIMS * D_DIM)          // 16000 flat (s,d) rows
#define ROW     (T_STEPS + 1)             // 3001 outputs per row
#define HALF_OUT ((long long)NJ * ROW)

#define NSIMB  250                        // sim blocks (4 sims each, 64 lanes)
#define GRID   256                        // ONE block per CU (r8 had 384: CU sharing regressed)
#define NPROD  7                          // producer waves per sim block (r6-proven)
#define DEPTH  32                         // LDS noise ring slots, pow2 (r6-proven)
#define BATCH  8                          // consumer speculation batch (r6-proven)
#define FILL_UNITS (S_SIMS * 2)           // half-sim (8 rows) per claim
#define SQSTEP 0.03162277660168379f       // sqrt(0.001)

__device__ uint2    g_keys[T_STEPS];
__device__ int      g_tf_pub[S_SIMS];               // -1 until published
__device__ unsigned g_c1;                           // fill work cursor
__device__ float    g_ws_pre[(size_t)T_STEPS * NJ]; // [t][j] prefix only

// ---------------------------------------------------------------------------
// Threefry-2x32 (20 rounds), bit-exact vs jax._src.prng (partitionable mode)
// ---------------------------------------------------------------------------
__device__ __forceinline__ uint32_t rotl32(uint32_t v, uint32_t d) {
  return (v << d) | (v >> (32u - d));
}
__device__ __forceinline__ void threefry2x32(uint32_t k0, uint32_t k1,
                                             uint32_t& x0, uint32_t& x1) {
  uint32_t k2 = k0 ^ k1 ^ 0x1BD11BDAu;
  x0 += k0; x1 += k1;
#define TFR(r) { x0 += x1; x1 = rotl32(x1, r); x1 ^= x0; }
  TFR(13u) TFR(15u) TFR(26u) TFR(6u)
  x0 += k1; x1 += k2 + 1u;
  TFR(17u) TFR(29u) TFR(16u) TFR(24u)
  x0 += k2; x1 += k0 + 2u;
  TFR(13u) TFR(15u) TFR(26u) TFR(6u)
  x0 += k0; x1 += k1 + 3u;
  TFR(17u) TFR(29u) TFR(16u) TFR(24u)
  x0 += k1; x1 += k2 + 4u;
  TFR(13u) TFR(15u) TFR(26u) TFR(6u)
  x0 += k2; x1 += k0 + 5u;
#undef TFR
}

// bits -> N(0,1): jax.random.normal f32 path (XLA ErfInv32 / Giles), with
// log1p(-u*u) = ln2*log2((1-u)(1+u)) via HW log (validated r6: absmax 0.002).
__device__ __forceinline__ float bits_to_normal(uint32_t bits) {
  uint32_t fb = (bits >> 9) | 0x3f800000u;
  float f = __uint_as_float(fb) - 1.0f;
  const float lo = -0.99999994f;
  float u = f * 2.0f + lo;
  u = fmaxf(lo, u);
  float w = -0.6931471805599453f * __log2f((1.0f - u) * (1.0f + u));
  float p;
  if (w < 5.0f) {
    w = w - 2.5f;
    p = 2.81022636e-08f;
    p = fmaf(p, w, 3.43273939e-07f);
    p = fmaf(p, w, -3.5233877e-06f);
    p = fmaf(p, w, -4.39150654e-06f);
    p = fmaf(p, w, 0.00021858087f);
    p = fmaf(p, w, -0.00125372503f);
    p = fmaf(p, w, -0.00417768164f);
    p = fmaf(p, w, 0.246640727f);
    p = fmaf(p, w, 1.50140941f);
  } else {
    w = sqrtf(w) - 3.0f;
    p = -0.000200214257f;
    p = fmaf(p, w, 0.000100950558f);
    p = fmaf(p, w, 0.00134934322f);
    p = fmaf(p, w, -0.00367342844f);
    p = fmaf(p, w, 0.00573950773f);
    p = fmaf(p, w, -0.0076224613f);
    p = fmaf(p, w, 0.00943887047f);
    p = fmaf(p, w, 1.00167406f);
    p = fmaf(p, w, 2.83297682f);
  }
  return 1.41421356237f * (p * u);
}

__device__ __forceinline__ float noise_at(int t, int j) {
  uint2 k = g_keys[t];
  uint32_t x0 = 0u, x1 = (uint32_t)j;
  threefry2x32(k.x, k.y, x0, x1);
  return bits_to_normal(x0 ^ x1);
}

// ---------------------------------------------------------------------------
// init: per-step keys (partitionable fold of split(key(42),T)) + queue state
// ---------------------------------------------------------------------------
__global__ void init_kernel() {
  int i = blockIdx.x * blockDim.x + threadIdx.x;
  if (i < T_STEPS) {
    uint32_t x0 = 0u, x1 = (uint32_t)i;
    threefry2x32(0u, 42u, x0, x1);
    g_keys[i] = make_uint2(x0, x1);
  }
  if (i < S_SIMS) g_tf_pub[i] = -1;
  if (i == 0) g_c1 = 0u;
}

// ---------------------------------------------------------------------------
// DPP reductions within each 16-lane row (one sim).
// ---------------------------------------------------------------------------
template <int CTRL>
__device__ __forceinline__ float dpp_movf(float v) {
  return __int_as_float(
      __builtin_amdgcn_update_dpp(0, __float_as_int(v), CTRL, 0xF, 0xF, true));
}
__device__ __forceinline__ float row16_sum(float a) {
  float s = a;
  s += dpp_movf<0xB1>(s);
  s += dpp_movf<0x4E>(s);
  s += dpp_movf<0x124>(s);
  s += dpp_movf<0x128>(s);
  return s;
}
__device__ __forceinline__ float row16_max(float a) {  // a >= 0
  float m = a;
  m = fmaxf(m, dpp_movf<0xB1>(m));
  m = fmaxf(m, dpp_movf<0x4E>(m));
  m = fmaxf(m, dpp_movf<0x124>(m));
  m = fmaxf(m, dpp_movf<0x128>(m));
  return m;
}

// ---------------------------------------------------------------------------
// Fused kernel: blocks [0,250) = r6-style sim (1 consumer + 7 producer waves,
// 512 threads, dedicated CU); every wave falls through to a per-wave fill
// loop claiming half-sims (8 rows). tf published per-sim (agent release);
// fillers acquire before ws reads (protocol validated r7/r8 under replays).
// ---------------------------------------------------------------------------
__global__ __launch_bounds__(512) void fused_kernel(const float* __restrict__ ff,
                                                    float* __restrict__ out) {
  __shared__ float sh_nbuf[DEPTH][64];
  __shared__ volatile unsigned sh_prodc[NPROD];  // per-producer completed count
  __shared__ volatile unsigned sh_cons;          // consumer watermark
  __shared__ volatile unsigned sh_done;

  const int tid  = threadIdx.x;
  const int lane = tid & 63;
  const int wid  = tid >> 6;

  if (blockIdx.x < NSIMB) {
    if (tid < NPROD) sh_prodc[tid] = 0u;
    if (tid == 0) { sh_cons = 0u; sh_done = 0u; }
    __syncthreads();
    const int j = blockIdx.x * 64 + lane;        // s = j>>4, d = j&15

    if (wid == 0) {
      // ============ consumer: LCA dynamics, batch-8 speculative (r6) ========
      __builtin_amdgcn_s_setprio(1);
      const float ffv = ff[j];
      float pre = 0.0f, act = 0.0f;
      bool dead = false;
      unsigned Rc = 0;   // steps < Rc are known produced

#define ENSURE(x)                                                     \
      while (Rc <= (unsigned)(x)) {                                   \
        unsigned mn = 0xffffffffu;                                    \
        for (int p_ = 0; p_ < NPROD; ++p_) {                          \
          unsigned lim = (unsigned)p_ + (unsigned)NPROD * sh_prodc[p_]; \
          if (lim < mn) mn = lim;                                     \
        }                                                             \
        Rc = mn;                                                      \
        if (Rc <= (unsigned)(x)) __builtin_amdgcn_s_sleep(2);         \
      }

      float n[BATCH], nn[BATCH], a[BATCH];
      ENSURE(BATCH - 1);
#pragma unroll
      for (int k = 0; k < BATCH; ++k) n[k] = sh_nbuf[k][lane];

      int t0 = 0;
      while (true) {
        if (lane == 0) sh_cons = (unsigned)(t0 + BATCH);
        const bool more = (t0 + BATCH < T_STEPS);
        if (more) {
          ENSURE(t0 + 2 * BATCH - 1);
#pragma unroll
          for (int k = 0; k < BATCH; ++k)
            nn[k] = sh_nbuf[(t0 + BATCH + k) & (DEPTH - 1)][lane];
        }

        float bmax = 0.0f;
        float* __restrict__ wsp = g_ws_pre + (size_t)t0 * NJ + j;
#pragma unroll
        for (int k = 0; k < BATCH; ++k) {
          float s  = row16_sum(act);
          float e1 = fmaf(-0.1f, pre, ffv);          // ff - leak*pre
          float e2 = fmaf(-0.1f, s - act, e1);       // - competition*(sum-self)
          pre = fmaf(e2, 0.01f, pre);                // + expr*dt
          pre = fmaf(n[k], SQSTEP, pre);             // + dw*sqrt(0.001)
          act = fmaxf(pre, 0.0f);
          a[k] = act;
          bmax = fmaxf(bmax, act);
          if (!dead) wsp[(size_t)k * NJ] = pre;
        }

        if (__any(bmax >= 1.0f)) {                   // rare
          bool found = dead;
          int ctf = 0;
#pragma unroll
          for (int k = 0; k < BATCH; ++k) {
            float m = row16_max(a[k]);               // row-uniform
            if (!found && m >= 1.0f) { found = true; ctf = t0 + k + 1; }
          }
          if (found && !dead) {                      // this row just crossed
            dead = true;
            pre = -1e30f;                            // relu pins act=0 forever
            act = 0.0f;
            if ((lane & 15) == 0)
              __hip_atomic_store(&g_tf_pub[j >> 4], ctf,
                                 __ATOMIC_RELEASE, __HIP_MEMORY_SCOPE_AGENT);
          }
          if (__all(dead)) break;
        }

        if (!more) break;
#pragma unroll
        for (int k = 0; k < BATCH; ++k) n[k] = nn[k];
        t0 += BATCH;
      }
#undef ENSURE
      if (!dead && (lane & 15) == 0)                 // horizon survivors
        __hip_atomic_store(&g_tf_pub[j >> 4], T_STEPS,
                           __ATOMIC_RELEASE, __HIP_MEMORY_SCOPE_AGENT);
      if (lane == 0) sh_done = 1u;
      __builtin_amdgcn_s_setprio(0);
    } else {
      // ============ producers: noise for t ≡ p (mod NPROD) (r6) =============
      const int p = wid - 1;
      unsigned count = 0;
      bool quit = false;
      for (int t = p; t < T_STEPS; t += NPROD) {
        if (sh_done) break;
        float nv = noise_at(t, j);
        if (t >= DEPTH) {
          while (true) {
            if (sh_done) { quit = true; break; }
            unsigned pc = sh_cons;
            if ((unsigned)t <= pc + (DEPTH - 1)) break;
            __builtin_amdgcn_s_sleep(4);
          }
          if (quit) break;
        }
        sh_nbuf[t & (DEPTH - 1)][lane] = nv;
        asm volatile("s_waitcnt lgkmcnt(0)" ::: "memory");
        ++count;
        if (lane == 0) sh_prodc[p] = count;
      }
    }
    // fall through to fill phase, per wave (no block re-convergence needed)
  }

  // ============ fill phase: per-wave half-sim (8-row) claiming ==============
  while (true) {
    unsigned u = 0;
    if (lane == 0) u = atomicAdd(&g_c1, 1u);
    u = (unsigned)__shfl((int)u, 0);
    if (u >= FILL_UNITS) break;
    const int s     = (int)(u >> 1);
    const int jbase = s * 16 + (int)(u & 1u) * 8;

    int tf = __hip_atomic_load(&g_tf_pub[s], __ATOMIC_RELAXED,
                               __HIP_MEMORY_SCOPE_AGENT);
    while (tf < 0) {                                 // park until sim publishes
      __builtin_amdgcn_s_sleep(8);
      tf = __hip_atomic_load(&g_tf_pub[s], __ATOMIC_RELAXED,
                             __HIP_MEMORY_SCOPE_AGENT);
    }
    (void)__hip_atomic_load(&g_tf_pub[s], __ATOMIC_ACQUIRE,
                            __HIP_MEMORY_SCOPE_AGENT);  // order ws reads

    // Chunk-major, row-inner: ws cachelines (te, s) fetched once, reused 8x
    // in L1 (working set ~4 KB). Writes fully coalesced per row.
    const int tclamp = tf - 1;
    for (int c = 0; c < ROW; c += 64) {
      const int idx = c + lane;
      if (idx >= ROW) break;
      const int te = (idx - 1 < tclamp) ? idx - 1 : tclamp;
      const float* __restrict__ wsrow = g_ws_pre + (size_t)te * NJ + jbase;
#pragma unroll
      for (int d = 0; d < 8; ++d) {
        float v = (idx == 0) ? 0.0f : wsrow[d];
        float* __restrict__ pre_out = out + (size_t)(jbase + d) * ROW;
        pre_out[idx] = v;
        (pre_out + HALF_OUT)[idx] = fmaxf(v, 0.0f);
      }
    }
  }
}

// ---------------------------------------------------------------------------
extern "C" void kernel_launch(void* const* d_in, const int* in_sizes, int n_in,
                              void* d_out, int out_size, void* d_ws, size_t ws_size,
                              hipStream_t stream) {
  const float* ff = (const float*)d_in[0];
  float* out = (float*)d_out;

  init_kernel<<<dim3(16), dim3(256), 0, stream>>>();
  fused_kernel<<<dim3(GRID), dim3(512), 0, stream>>>(ff, out);
}

// Round 10
// 106.297 us; speedup vs baseline: 17.8679x; 1.7009x over previous
//
#include <hip/hip_runtime.h>
#include <cstdint>

// LCA model constants
#define T_STEPS 3000
#define S_SIMS  1000
#define D_DIM   16
#define NJ      (S_SIMS * D_DIM)          // 16000 flat (s,d) rows
#define ROW     (T_STEPS + 1)             // 3001 outputs per row
#define HALF_OUT ((long long)NJ * ROW)

#define NSIMB  250                        // blocks: 4 sims each, 64 rows each
#define NPROD  7                          // producer waves (r6-proven)
#define DEPTH  32                         // LDS noise ring slots (r6-proven)
#define BATCH  8                          // consumer speculation batch (r6-proven)
#define PAD_FLOATS 13000                  // LDS pad -> ~84KB total -> 1 block/CU
#define SQSTEP 0.03162277660168379f       // sqrt(0.001)

__device__ float g_ws_pre[(size_t)T_STEPS * NJ];  // [t][j] prefix only

// ---------------------------------------------------------------------------
// Threefry-2x32 (20 rounds), bit-exact vs jax._src.prng (partitionable mode)
// ---------------------------------------------------------------------------
__device__ __forceinline__ uint32_t rotl32(uint32_t v, uint32_t d) {
  return (v << d) | (v >> (32u - d));
}
__device__ __forceinline__ void threefry2x32(uint32_t k0, uint32_t k1,
                                             uint32_t& x0, uint32_t& x1) {
  uint32_t k2 = k0 ^ k1 ^ 0x1BD11BDAu;
  x0 += k0; x1 += k1;
#define TFR(r) { x0 += x1; x1 = rotl32(x1, r); x1 ^= x0; }
  TFR(13u) TFR(15u) TFR(26u) TFR(6u)
  x0 += k1; x1 += k2 + 1u;
  TFR(17u) TFR(29u) TFR(16u) TFR(24u)
  x0 += k2; x1 += k0 + 2u;
  TFR(13u) TFR(15u) TFR(26u) TFR(6u)
  x0 += k0; x1 += k1 + 3u;
  TFR(17u) TFR(29u) TFR(16u) TFR(24u)
  x0 += k1; x1 += k2 + 4u;
  TFR(13u) TFR(15u) TFR(26u) TFR(6u)
  x0 += k2; x1 += k0 + 5u;
#undef TFR
}

// bits -> N(0,1): jax.random.normal f32 path (XLA ErfInv32 / Giles), with
// log1p(-u*u) = ln2*log2((1-u)(1+u)) via HW log (validated r6: absmax 0.002).
__device__ __forceinline__ float bits_to_normal(uint32_t bits) {
  uint32_t fb = (bits >> 9) | 0x3f800000u;
  float f = __uint_as_float(fb) - 1.0f;
  const float lo = -0.99999994f;
  float u = f * 2.0f + lo;
  u = fmaxf(lo, u);
  float w = -0.6931471805599453f * __log2f((1.0f - u) * (1.0f + u));
  float p;
  if (w < 5.0f) {
    w = w - 2.5f;
    p = 2.81022636e-08f;
    p = fmaf(p, w, 3.43273939e-07f);
    p = fmaf(p, w, -3.5233877e-06f);
    p = fmaf(p, w, -4.39150654e-06f);
    p = fmaf(p, w, 0.00021858087f);
    p = fmaf(p, w, -0.00125372503f);
    p = fmaf(p, w, -0.00417768164f);
    p = fmaf(p, w, 0.246640727f);
    p = fmaf(p, w, 1.50140941f);
  } else {
    w = sqrtf(w) - 3.0f;
    p = -0.000200214257f;
    p = fmaf(p, w, 0.000100950558f);
    p = fmaf(p, w, 0.00134934322f);
    p = fmaf(p, w, -0.00367342844f);
    p = fmaf(p, w, 0.00573950773f);
    p = fmaf(p, w, -0.0076224613f);
    p = fmaf(p, w, 0.00943887047f);
    p = fmaf(p, w, 1.00167406f);
    p = fmaf(p, w, 2.83297682f);
  }
  return 1.41421356237f * (p * u);
}

// ---------------------------------------------------------------------------
// DPP reductions within each 16-lane row (one sim).
// ---------------------------------------------------------------------------
template <int CTRL>
__device__ __forceinline__ float dpp_movf(float v) {
  return __int_as_float(
      __builtin_amdgcn_update_dpp(0, __float_as_int(v), CTRL, 0xF, 0xF, true));
}
__device__ __forceinline__ float row16_sum(float a) {
  float s = a;
  s += dpp_movf<0xB1>(s);
  s += dpp_movf<0x4E>(s);
  s += dpp_movf<0x124>(s);
  s += dpp_movf<0x128>(s);
  return s;
}
__device__ __forceinline__ float row16_max(float a) {  // a >= 0
  float m = a;
  m = fmaxf(m, dpp_movf<0xB1>(m));
  m = fmaxf(m, dpp_movf<0x4E>(m));
  m = fmaxf(m, dpp_movf<0x124>(m));
  m = fmaxf(m, dpp_movf<0x128>(m));
  return m;
}

// ---------------------------------------------------------------------------
// Single kernel: keys prologue (LDS) -> r6 producer-consumer sim ->
// block-local self-fill of the block's own 64 output rows.
// No cross-block communication of any kind. LDS padded to ~84KB so only
// ONE block fits per CU (removes scheduler-packing unknown; producers
// saturate CU issue, a co-resident block would double step time).
// ---------------------------------------------------------------------------
__global__ __launch_bounds__(512) void lca_kernel(const float* __restrict__ ff,
                                                  float* __restrict__ out) {
  __shared__ uint2 sh_keys[T_STEPS];             // 24.0 KB
  __shared__ float sh_nbuf[DEPTH][64];           //  8.2 KB
  __shared__ float sh_pad[PAD_FLOATS];           // 52.0 KB occupancy pad
  __shared__ volatile unsigned sh_prodc[NPROD];
  __shared__ volatile unsigned sh_cons;
  __shared__ volatile unsigned sh_done;
  __shared__ int sh_tf[4];

  const int tid  = threadIdx.x;
  const int lane = tid & 63;
  const int wid  = tid >> 6;
  const int j    = blockIdx.x * 64 + lane;       // s = j>>4, d = j&15

  // ---- prologue: all 3000 step keys into LDS (partitionable fold) ----
  for (int i = tid; i < T_STEPS; i += 512) {
    uint32_t x0 = 0u, x1 = (uint32_t)i;
    threefry2x32(0u, 42u, x0, x1);
    sh_keys[i] = make_uint2(x0, x1);
  }
  { volatile float* vp = sh_pad; vp[tid] = 0.0f; }   // keep pad alive
  if (tid < NPROD) sh_prodc[tid] = 0u;
  if (tid == 0) { sh_cons = 0u; sh_done = 0u; }
  __syncthreads();

  if (wid == 0) {
    // ============ consumer: LCA dynamics, batch-8 speculative (r6) ==========
    __builtin_amdgcn_s_setprio(1);
    const float ffv = ff[j];
    float pre = 0.0f, act = 0.0f;
    bool dead = false;
    int my_tf = T_STEPS;
    unsigned Rc = 0;   // steps < Rc are known produced

#define ENSURE(x)                                                     \
    while (Rc <= (unsigned)(x)) {                                     \
      unsigned mn = 0xffffffffu;                                      \
      for (int p_ = 0; p_ < NPROD; ++p_) {                            \
        unsigned lim = (unsigned)p_ + (unsigned)NPROD * sh_prodc[p_]; \
        if (lim < mn) mn = lim;                                       \
      }                                                               \
      Rc = mn;                                                        \
      if (Rc <= (unsigned)(x)) __builtin_amdgcn_s_sleep(2);           \
    }

    float n[BATCH], nn[BATCH], a[BATCH];
    ENSURE(BATCH - 1);
#pragma unroll
    for (int k = 0; k < BATCH; ++k) n[k] = sh_nbuf[k][lane];

    int t0 = 0;
    while (true) {
      if (lane == 0) sh_cons = (unsigned)(t0 + BATCH);
      const bool more = (t0 + BATCH < T_STEPS);
      if (more) {
        ENSURE(t0 + 2 * BATCH - 1);
#pragma unroll
        for (int k = 0; k < BATCH; ++k)
          nn[k] = sh_nbuf[(t0 + BATCH + k) & (DEPTH - 1)][lane];
      }

      float bmax = 0.0f;
      float* __restrict__ wsp = g_ws_pre + (size_t)t0 * NJ + j;
#pragma unroll
      for (int k = 0; k < BATCH; ++k) {
        float s  = row16_sum(act);
        float e1 = fmaf(-0.1f, pre, ffv);          // ff - leak*pre
        float e2 = fmaf(-0.1f, s - act, e1);       // - competition*(sum-self)
        pre = fmaf(e2, 0.01f, pre);                // + expr*dt
        pre = fmaf(n[k], SQSTEP, pre);             // + dw*sqrt(0.001)
        act = fmaxf(pre, 0.0f);
        a[k] = act;
        bmax = fmaxf(bmax, act);
        if (!dead) wsp[(size_t)k * NJ] = pre;
      }

      if (__any(bmax >= 1.0f)) {                   // rare: <=4x per wave
        bool found = dead;
        int ctf = 0;
#pragma unroll
        for (int k = 0; k < BATCH; ++k) {
          float m = row16_max(a[k]);               // row-uniform
          if (!found && m >= 1.0f) { found = true; ctf = t0 + k + 1; }
        }
        if (found && !dead) {                      // this row just crossed
          dead = true;
          my_tf = ctf;
          pre = -1e30f;                            // relu pins act=0 forever
          act = 0.0f;
        }
        if (__all(dead)) break;
      }

      if (!more) break;
#pragma unroll
      for (int k = 0; k < BATCH; ++k) n[k] = nn[k];
      t0 += BATCH;
    }
#undef ENSURE
    if ((lane & 15) == 0) sh_tf[lane >> 4] = my_tf;  // row-uniform, 1<=tf<=3000
    if (lane == 0) sh_done = 1u;
    __builtin_amdgcn_s_setprio(0);
  } else {
    // ============ producers: noise for t ≡ p (mod NPROD) (r6) ===============
    const int p = wid - 1;
    unsigned count = 0;
    bool quit = false;
    for (int t = p; t < T_STEPS; t += NPROD) {
      if (sh_done) break;
      uint2 k = sh_keys[t];
      uint32_t x0 = 0u, x1 = (uint32_t)j;
      threefry2x32(k.x, k.y, x0, x1);
      float nv = bits_to_normal(x0 ^ x1);
      if (t >= DEPTH) {
        while (true) {
          if (sh_done) { quit = true; break; }
          unsigned pc = sh_cons;
          if ((unsigned)t <= pc + (DEPTH - 1)) break;
          __builtin_amdgcn_s_sleep(4);
        }
        if (quit) break;
      }
      sh_nbuf[t & (DEPTH - 1)][lane] = nv;
      asm volatile("s_waitcnt lgkmcnt(0)" ::: "memory");
      ++count;
      if (lane == 0) sh_prodc[p] = count;
    }
  }

  __syncthreads();   // sh_tf visible; consumer's ws writes drained (vmcnt(0))

  // ============ self-fill: wave wid fills rows [wid*8, wid*8+8) =============
  const int r0 = wid * 8;
#pragma unroll 1
  for (int r = 0; r < 8; ++r) {
    const int jr = blockIdx.x * 64 + r0 + r;
    const int tf = sh_tf[(r0 + r) >> 4];
    float* __restrict__ pre_out = out + (size_t)jr * ROW;
    float* __restrict__ act_out = pre_out + HALF_OUT;
    const float vlast = g_ws_pre[(size_t)(tf - 1) * NJ + jr];  // broadcast read
    // prefix (incl idx=0): out[idx] = idx==0 ? 0 : ws[idx-1]
    for (int idx = lane; idx <= tf; idx += 64) {
      float v = (idx == 0) ? 0.0f : g_ws_pre[(size_t)(idx - 1) * NJ + jr];
      pre_out[idx] = v;
      act_out[idx] = fmaxf(v, 0.0f);
    }
    // frozen tail: pure streaming stores, no loads
    const float va = fmaxf(vlast, 0.0f);
    for (int idx = tf + 1 + lane; idx <= T_STEPS; idx += 64) {
      pre_out[idx] = vlast;
      act_out[idx] = va;
    }
  }
}

// ---------------------------------------------------------------------------
extern "C" void kernel_launch(void* const* d_in, const int* in_sizes, int n_in,
                              void* d_out, int out_size, void* d_ws, size_t ws_size,
                              hipStream_t stream) {
  const float* ff = (const float*)d_in[0];
  float* out = (float*)d_out;

  lca_kernel<<<dim3(NSIMB), dim3(512), 0, stream>>>(ff, out);
}